// Round 17
// baseline (57.360 us; speedup 1.0000x reference)
//
#include <hip/hip_runtime.h>
#include <hip/hip_bf16.h>

#define HW 16384
#define W_IMG 128
#define BM_TOT 5
#define PRE 0.5101179482f   // (1/sqrt(8)) * log2(e): folded into Q so p = exp2(s)

typedef __attribute__((ext_vector_type(8))) short bf16x8;
typedef __attribute__((ext_vector_type(4))) float f32x4;

__device__ __forceinline__ short f2b(float f) {
    __hip_bfloat16 h = __float2bfloat16(f);
    union { __hip_bfloat16 h; short s; } c; c.h = h; return c.s;
}
__device__ __forceinline__ float b2f(short s) {
    union { unsigned u; float f; } v; v.u = ((unsigned)(unsigned short)s) << 16;
    return v.f;
}
__device__ __forceinline__ unsigned pk2(float a, float b) {   // -> v_cvt_pk_bf16_f32
    __hip_bfloat162 h = __float22bfloat162_rn(make_float2(a, b));
    union { __hip_bfloat162 h; unsigned u; } c; c.h = h; return c.u;
}
__device__ __forceinline__ float fexp2(float x) {             // ONE v_exp_f32, no libcall
#if __has_builtin(__builtin_amdgcn_exp2f)
    return __builtin_amdgcn_exp2f(x);
#else
    float r; asm("v_exp_f32 %0, %1" : "=v"(r) : "v"(x)); return r;
#endif
}

// ---------------------------------------------------------------------------
// Kernel 1: conv+LN + featRGB + MFMA QKV projection. (round-16, unchanged)
// ---------------------------------------------------------------------------
__global__ __launch_bounds__(256) void k_qkv(
    const float* __restrict__ x, const float* __restrict__ w_qkv,
    const float* __restrict__ w_high, const float* __restrict__ b_high,
    const float* __restrict__ gamma, const float* __restrict__ beta,
    const float* __restrict__ pos_q, const float* __restrict__ w_rgb,
    const float* __restrict__ w_out,
    float* __restrict__ featrgb, short* __restrict__ qmid,
    short* __restrict__ kbuf, short* __restrict__ vbuf,
    short* __restrict__ wcombb)
{
    __shared__ char smem[21248];
    short* XS  = (short*)smem;                 // [64][72] bf16 normalized acts
    short* TLv = (short*)(smem + 9216);        // [64][72] V staging (transpose)
    float* WL  = (float*)(smem + 18432);       // [64][8] conv/LN table
    float* WRL = (float*)(smem + 20480);       // [192] w_rgb

    const int tid = threadIdx.x, blk = blockIdx.x;
    const int bm = blk >> 8, p0 = (blk & 255) * 64;
    const int pixbase = blk * 64;
    const int wv = tid >> 6, lane = tid & 63;
    const int col = lane & 15, grp = lane >> 4;

    // ---- issue x loads FIRST (independent of LDS tables) ----
    const int px_l = tid >> 2, part = tid & 3;
    const int p_glob = p0 + px_l;
    const float* xp = x + (size_t)bm * 3 * HW + p_glob;
    const float x0 = xp[0], x1 = xp[HW], x2 = xp[2 * HW];

    // ---- build weight tables in LDS (tiny, L2-hot) ----
    if (tid < 64) {
        WL[tid * 8 + 0] = w_high[tid * 3];
        WL[tid * 8 + 1] = w_high[tid * 3 + 1];
        WL[tid * 8 + 2] = w_high[tid * 3 + 2];
        WL[tid * 8 + 3] = b_high[tid];
        WL[tid * 8 + 4] = gamma[tid];
        WL[tid * 8 + 5] = beta[tid];
    } else if (tid < 112) {
        ((float4*)WRL)[tid - 64] = ((const float4*)w_rgb)[tid - 64];
    }
    __syncthreads();

    // ---- conv + LN + rgb-residual: 4 threads/pixel, 16 channels each ----
    {
        float f[16]; float s = 0.f, s2 = 0.f;
        #pragma unroll
        for (int j = 0; j < 16; ++j) {
            const int ch = part * 16 + j;
            float4 wa = *(const float4*)&WL[ch * 8];
            f[j] = fmaf(wa.x, x0, fmaf(wa.y, x1, fmaf(wa.z, x2, wa.w)));
            s += f[j]; s2 = fmaf(f[j], f[j], s2);
        }
        float r0 = 0.f, r1 = 0.f, r2 = 0.f;
        #pragma unroll
        for (int j = 0; j < 16; ++j) {
            const float fj = f[j];
            r0 = fmaf(fj, WRL[part * 16 + j], r0);
            r1 = fmaf(fj, WRL[64 + part * 16 + j], r1);
            r2 = fmaf(fj, WRL[128 + part * 16 + j], r2);
        }
        s  += __shfl_xor(s, 1);  s  += __shfl_xor(s, 2);
        s2 += __shfl_xor(s2, 1); s2 += __shfl_xor(s2, 2);
        r0 += __shfl_xor(r0, 1); r0 += __shfl_xor(r0, 2);
        r1 += __shfl_xor(r1, 1); r1 += __shfl_xor(r1, 2);
        r2 += __shfl_xor(r2, 1); r2 += __shfl_xor(r2, 2);
        if (part < 3) {
            float rv = part == 0 ? r0 : (part == 1 ? r1 : r2);
            featrgb[((size_t)bm * 3 + part) * HW + p_glob] = rv;
        }
        const float mu = s * 0.015625f;
        const float var = s2 * 0.015625f - mu * mu;
        const float rs = rsqrtf(var + 1e-6f);
        unsigned xw[8];
        #pragma unroll
        for (int j2 = 0; j2 < 8; ++j2) {
            const int ch = part * 16 + 2 * j2;
            float4 g0 = *(const float4*)&WL[ch * 8 + 4];
            float4 g1 = *(const float4*)&WL[ch * 8 + 12];
            xw[j2] = pk2((f[2 * j2] - mu) * rs * g0.x + g0.y,
                         (f[2 * j2 + 1] - mu) * rs * g1.x + g1.y);
        }
        *(uint4*)&XS[px_l * 72 + part * 16]     = make_uint4(xw[0], xw[1], xw[2], xw[3]);
        *(uint4*)&XS[px_l * 72 + part * 16 + 8] = make_uint4(xw[4], xw[5], xw[6], xw[7]);
    }

    // ---- B-fragments packed from f32 w_qkv via float4 loads ----
    bf16x8 Bf[3][2];
    #pragma unroll
    for (int jj = 0; jj < 3; ++jj) {
        int jt = wv + jj * 4;
        #pragma unroll
        for (int kc = 0; kc < 2; ++kc) {
            const float4* src = (const float4*)&w_qkv[(jt * 16 + col) * 64 + kc * 32 + grp * 8];
            float4 a = src[0], b = src[1];
            union { bf16x8 v; unsigned u[4]; } tmp;
            tmp.u[0] = pk2(a.x, a.y); tmp.u[1] = pk2(a.z, a.w);
            tmp.u[2] = pk2(b.x, b.y); tmp.u[3] = pk2(b.z, b.w);
            Bf[jj][kc] = tmp.v;
        }
    }
    __syncthreads();

    // ---- MFMA projection; K and Q stored DIRECTLY to global ----
    #pragma unroll
    for (int pt = 0; pt < 4; ++pt) {
        bf16x8 A0 = *(const bf16x8*)&XS[(pt * 16 + col) * 72 + grp * 8];
        bf16x8 A1 = *(const bf16x8*)&XS[(pt * 16 + col) * 72 + 32 + grp * 8];

        f32x4 aK = {0.f, 0.f, 0.f, 0.f};
        aK = __builtin_amdgcn_mfma_f32_16x16x32_bf16(Bf[1][0], A0, aK, 0, 0, 0);
        aK = __builtin_amdgcn_mfma_f32_16x16x32_bf16(Bf[1][1], A1, aK, 0, 0, 0);
        uint2 kw = {pk2(aK[0], aK[1]), pk2(aK[2], aK[3])};
        *(uint2*)&kbuf[((size_t)pixbase + pt * 16 + col) * 64 + wv * 16 + grp * 4] = kw;

        f32x4 aV = {0.f, 0.f, 0.f, 0.f};
        aV = __builtin_amdgcn_mfma_f32_16x16x32_bf16(A0, Bf[2][0], aV, 0, 0, 0);
        aV = __builtin_amdgcn_mfma_f32_16x16x32_bf16(A1, Bf[2][1], aV, 0, 0, 0);
        #pragma unroll
        for (int i = 0; i < 4; ++i)
            TLv[(pt * 16 + grp * 4 + i) * 72 + wv * 16 + col] = f2b(aV[i]);

        if (bm == 2) {
            f32x4 aQ = {0.f, 0.f, 0.f, 0.f};
            aQ = __builtin_amdgcn_mfma_f32_16x16x32_bf16(Bf[0][0], A0, aQ, 0, 0, 0);
            aQ = __builtin_amdgcn_mfma_f32_16x16x32_bf16(Bf[0][1], A1, aQ, 0, 0, 0);
            int p = p0 + pt * 16 + col;
            int qq = ((p >> 7) & 7) * 8 + (p & 7);
            float4 pq = *(const float4*)&pos_q[qq * 64 + wv * 16 + grp * 4];
            uint2 qw = {pk2((aQ[0] + pq.x) * PRE, (aQ[1] + pq.y) * PRE),
                        pk2((aQ[2] + pq.z) * PRE, (aQ[3] + pq.w) * PRE)};
            *(uint2*)&qmid[((size_t)p0 + pt * 16 + col) * 64 + wv * 16 + grp * 4] = qw;
        }
    }
    __syncthreads();

    // ---- coalesced copy-out: V only ----
    #pragma unroll
    for (int it = 0; it < 2; ++it) {
        int j = it * 256 + tid;
        int row = j >> 3, seg = j & 7;
        *(uint4*)&vbuf[((size_t)pixbase + row) * 64 + seg * 8] =
            *(const uint4*)&TLv[row * 72 + seg * 8];
    }

    // ---- block 0 tail: wcomb = w_rgb @ w_out; f32 w_out over dead XS+TLv ----
    if (blk == 0) {
        float* WOL = (float*)smem;
        __syncthreads();
        for (int i = tid; i < 4096; i += 256) WOL[i] = w_out[i];
        __syncthreads();
        for (int i = tid; i < 1024; i += 256) {
            short wc = 0;
            if (i < 192) {
                int c = i >> 6, e = i & 63;
                float a = 0.f;
                #pragma unroll 8
                for (int e2 = 0; e2 < 64; ++e2)
                    a = fmaf(WRL[c * 64 + e2], WOL[e2 * 64 + e], a);
                wc = f2b(a);
            }
            wcombb[i] = wc;
        }
    }
}

// ---------------------------------------------------------------------------
// Kernel 2: windowed attention + fused epilogue. Round-12 structure with
// r14's chain-shortening (dual PV accumulators, split l-sums) retried under
// the UNCLAMPED (512,4) bounds — r14's spill was the (512,6) 40-VGPR cap,
// not the edits (r15 proved (512,4) is occupancy-free up to 85 VGPRs).
// ---------------------------------------------------------------------------
__global__ __launch_bounds__(512, 4) void k_attn(
    const short* __restrict__ qmid, const short* __restrict__ kbuf,
    const short* __restrict__ vbuf,
    const float* __restrict__ pos_k, const float* __restrict__ b_rgb,
    const float* __restrict__ featrgb, const short* __restrict__ wcombb,
    float* __restrict__ outp)
{
    __shared__ char smem[48448];
    short* Klds = (short*)smem;                  // [144][72] bf16, K + pos_k
    short* Vt   = (short*)(smem + 20736);        // [64][152] bf16 + slack row 64
    short* OL   = (short*)smem;                  // overlay (head-column-sliced)
    // P slot buffers: smem + 40224, 1 KB per wave (8 waves)

    const int tid = threadIdx.x, blk = blockIdx.x;
    const int bm = blk >> 8, widx = blk & 255;
    const int wi = widx >> 4, wj = widx & 15;
    const int head = tid >> 6, lane = tid & 63;
    const int col = lane & 15, grp = lane >> 4;

    // ---- Q fragments first (independent loads, pos_q & scale pre-folded) ----
    uint4 qraw[4] = {{0,0,0,0},{0,0,0,0},{0,0,0,0},{0,0,0,0}};
    if (grp == 0) {
        #pragma unroll
        for (int qt = 0; qt < 4; ++qt) {
            int q = qt * 16 + col;
            int pix = (wi * 8 + (q >> 3)) * W_IMG + wj * 8 + (q & 7);
            qraw[qt] = *(const uint4*)&qmid[(size_t)pix * 64 + head * 8];
        }
    }

    // ---- wave-private staging: wave h covers keys lane, lane+64, lane+128 ----
    #pragma unroll
    for (int i = 0; i < 3; ++i) {
        const int kk = lane + i * 64;
        if (i == 2 && lane >= 16) continue;      // kk < 144
        const int r = kk / 12, c = kk - r * 12;
        const int hh = wi * 8 - 2 + r, ww = wj * 8 - 2 + c;
        uint4 kraw = {0, 0, 0, 0}, vraw = {0, 0, 0, 0};
        if ((unsigned)hh < 128u && (unsigned)ww < 128u) {
            size_t off = ((size_t)bm * HW + hh * W_IMG + ww) * 64 + head * 8;
            kraw = *(const uint4*)&kbuf[off];
            vraw = *(const uint4*)&vbuf[off];
        }
        const float* pk = &pos_k[kk * 64 + head * 8];
        float4 pk0 = *(const float4*)pk;
        float4 pk1 = *(const float4*)(pk + 4);
        union { uint4 q; short s[8]; } ku, vu;
        ku.q = kraw; vu.q = vraw;
        uint4 ko;
        ko.x = pk2(b2f(ku.s[0]) + pk0.x, b2f(ku.s[1]) + pk0.y);
        ko.y = pk2(b2f(ku.s[2]) + pk0.z, b2f(ku.s[3]) + pk0.w);
        ko.z = pk2(b2f(ku.s[4]) + pk1.x, b2f(ku.s[5]) + pk1.y);
        ko.w = pk2(b2f(ku.s[6]) + pk1.z, b2f(ku.s[7]) + pk1.w);
        *(uint4*)&Klds[kk * 72 + head * 8] = ko;
        #pragma unroll
        for (int cc = 0; cc < 8; ++cc)
            Vt[(head * 8 + cc) * 152 + kk] = vu.s[cc];
    }
    // zero this wave's Vt pad cols [144,152); wave 7 zeroes slack row 64 cols 0-7
    if (lane < 8) *(uint4*)&Vt[(head * 8 + lane) * 152 + 144] = (uint4){0, 0, 0, 0};
    if (head == 7 && lane == 0) *(uint4*)&Vt[64 * 152] = (uint4){0, 0, 0, 0};

    unsigned* PBh = (unsigned*)(smem + 40224 + head * 1024);
    const int slot_w = (grp * 16 + (col ^ grp)) * 4;
    const int g0 = 2 * (grp & 1);
    const int slotr1 = (g0 * 16 + (col ^ g0)) * 4 + (grp >> 1) * 2;
    const int slotr2 = ((g0 + 1) * 16 + (col ^ (g0 + 1))) * 4 + (grp >> 1) * 2;

    f32x4 oacc[4];
    float linv[4];

    #pragma unroll
    for (int qt = 0; qt < 4; ++qt) {
        union { bf16x8 v; uint4 r; } qu; qu.r = qraw[qt];
        const bf16x8 qf = qu.v;

        // ---- softmax, no max-subtract: p = exp2(s); split partial sums ----
        float l0 = 0.f, l1 = 0.f;
        unsigned pw[20];
        __builtin_amdgcn_s_setprio(1);
        #pragma unroll
        for (int t = 0; t < 9; ++t) {
            bf16x8 kf = *(const bf16x8*)&Klds[(t * 16 + col) * 72 + head * 8];
            f32x4 sct = __builtin_amdgcn_mfma_f32_16x16x32_bf16(
                kf, qf, (f32x4){0.f, 0.f, 0.f, 0.f}, 0, 0, 0);
            float e0 = fexp2(sct[0]), e1 = fexp2(sct[1]);
            float e2 = fexp2(sct[2]), e3 = fexp2(sct[3]);
            if (t & 1) l1 += (e0 + e1) + (e2 + e3);
            else       l0 += (e0 + e1) + (e2 + e3);
            pw[2 * t]     = pk2(e0, e1);
            pw[2 * t + 1] = pk2(e2, e3);
        }
        __builtin_amdgcn_s_setprio(0);
        pw[18] = 0u; pw[19] = 0u;
        float l = l0 + l1;
        l += __shfl_xor(l, 16);
        l += __shfl_xor(l, 32);
        linv[qt] = __builtin_amdgcn_rcpf(l);

        // ---- PV: O^T = V^T . P^T; dual accumulators halve the MFMA chain ----
        *(uint4*)(PBh + slot_w) = make_uint4(pw[0], pw[1], pw[2], pw[3]);
        f32x4 oa0 = {0.f, 0.f, 0.f, 0.f}, oa1 = {0.f, 0.f, 0.f, 0.f};
        __builtin_amdgcn_s_setprio(1);
        #pragma unroll
        for (int kt2 = 0; kt2 < 5; ++kt2) {
            uint2 r1 = *(const uint2*)(PBh + slotr1);
            uint2 r2 = *(const uint2*)(PBh + slotr2);
            if (kt2 < 4)
                *(uint4*)(PBh + slot_w) =
                    make_uint4(pw[4 * kt2 + 4], pw[4 * kt2 + 5], pw[4 * kt2 + 6], pw[4 * kt2 + 7]);
            union { bf16x8 v; unsigned u[4]; } pf;
            pf.u[0] = r1.x; pf.u[1] = r1.y; pf.u[2] = r2.x; pf.u[3] = r2.y;
            bf16x8 vf = *(const bf16x8*)&Vt[(head * 8 + (lane & 7)) * 152 + kt2 * 32 + grp * 8];
            if (kt2 & 1)
                oa1 = __builtin_amdgcn_mfma_f32_16x16x32_bf16(vf, pf.v, oa1, 0, 0, 0);
            else
                oa0 = __builtin_amdgcn_mfma_f32_16x16x32_bf16(vf, pf.v, oa0, 0, 0, 0);
        }
        __builtin_amdgcn_s_setprio(0);
        oacc[qt][0] = oa0[0] + oa1[0];
        oacc[qt][1] = oa0[1] + oa1[1];
        oacc[qt][2] = oa0[2] + oa1[2];
        oacc[qt][3] = oa0[3] + oa1[3];
    }

    // ---- OL write: overlays THIS wave's own Klds column slice (in-order) ----
    if (grp < 2) {
        #pragma unroll
        for (int qt = 0; qt < 4; ++qt) {
            float s = linv[qt];
            uint2 ow;
            ow.x = pk2(oacc[qt][0] * s, oacc[qt][1] * s);
            ow.y = pk2(oacc[qt][2] * s, oacc[qt][3] * s);
            *(uint2*)&OL[(qt * 16 + col) * 72 + head * 8 + grp * 4] = ow;
        }
    }
    __syncthreads();   // the ONLY barrier: epilogue reads OL across heads

    // ---- fused epilogue: rgb = O@wcomb^T + featrgb + b_rgb (waves 0-3) ----
    if (head < 4) {
        const int qt = head;
        f32x4 acc = {0.f, 0.f, 0.f, 0.f};
        #pragma unroll
        for (int kc = 0; kc < 2; ++kc) {
            bf16x8 ao = *(const bf16x8*)&OL[(qt * 16 + col) * 72 + kc * 32 + grp * 8];
            bf16x8 bo = *(const bf16x8*)&wcombb[col * 64 + kc * 32 + grp * 8];
            acc = __builtin_amdgcn_mfma_f32_16x16x32_bf16(ao, bo, acc, 0, 0, 0);
        }
        if (col < 3) {
            float br = b_rgb[col];
            const float* frp = featrgb + ((size_t)bm * 3 + col) * HW;
            #pragma unroll
            for (int i = 0; i < 4; ++i) {
                int qs = qt * 16 + grp * 4 + i;
                int pix = (wi * 8 + (qs >> 3)) * W_IMG + wj * 8 + (qs & 7);
                outp[(size_t)bm * 3 * HW + col * HW + pix] = acc[i] + frp[pix] + br;
            }
        }
    }
}

// ---------------------------------------------------------------------------
extern "C" void kernel_launch(void* const* d_in, const int* in_sizes, int n_in,
                              void* d_out, int out_size, void* d_ws, size_t ws_size,
                              hipStream_t stream) {
    const float* x      = (const float*)d_in[0];
    const float* w_high = (const float*)d_in[1];
    const float* b_high = (const float*)d_in[2];
    const float* gamma  = (const float*)d_in[3];
    const float* beta   = (const float*)d_in[4];
    const float* w_qkv  = (const float*)d_in[5];
    const float* pos_q  = (const float*)d_in[6];
    const float* pos_k  = (const float*)d_in[7];
    const float* w_out  = (const float*)d_in[8];
    const float* w_rgb  = (const float*)d_in[9];
    const float* b_rgb  = (const float*)d_in[10];
    float* out = (float*)d_out;

    float* featrgb = (float*)d_ws;                         // [5][3][HW] f32
    short* kbuf    = (short*)(featrgb + (size_t)BM_TOT * 3 * HW);
    short* vbuf    = kbuf + (size_t)BM_TOT * HW * 64;
    short* qmid    = vbuf + (size_t)BM_TOT * HW * 64;      // [HW][64]
    short* wcombb  = qmid + (size_t)HW * 64;               // [16][64]

    k_qkv<<<BM_TOT * 256, 256, 0, stream>>>(x, w_qkv, w_high, b_high, gamma, beta,
                                            pos_q, w_rgb, w_out,
                                            featrgb, qmid, kbuf, vbuf, wcombb);
    k_attn<<<BM_TOT * 256, 512, 0, stream>>>(qmid, kbuf, vbuf, pos_k,
                                             b_rgb, featrgb, wcombb, out);
}

// Round 18
// 53.890 us; speedup vs baseline: 1.0644x; 1.0644x over previous
//
#include <hip/hip_runtime.h>
#include <hip/hip_bf16.h>

#define HW 16384
#define W_IMG 128
#define BM_TOT 5
#define PRE 0.5101179482f   // (1/sqrt(8)) * log2(e): folded into Q so p = exp2(s)

typedef __attribute__((ext_vector_type(8))) short bf16x8;
typedef __attribute__((ext_vector_type(4))) float f32x4;

__device__ __forceinline__ short f2b(float f) {
    __hip_bfloat16 h = __float2bfloat16(f);
    union { __hip_bfloat16 h; short s; } c; c.h = h; return c.s;
}
__device__ __forceinline__ float b2f(short s) {
    union { unsigned u; float f; } v; v.u = ((unsigned)(unsigned short)s) << 16;
    return v.f;
}
__device__ __forceinline__ unsigned pk2(float a, float b) {   // -> v_cvt_pk_bf16_f32
    __hip_bfloat162 h = __float22bfloat162_rn(make_float2(a, b));
    union { __hip_bfloat162 h; unsigned u; } c; c.h = h; return c.u;
}
__device__ __forceinline__ float fexp2(float x) {             // ONE v_exp_f32, no libcall
#if __has_builtin(__builtin_amdgcn_exp2f)
    return __builtin_amdgcn_exp2f(x);
#else
    float r; asm("v_exp_f32 %0, %1" : "=v"(r) : "v"(x)); return r;
#endif
}

// ---------------------------------------------------------------------------
// Kernel 1: conv+LN + featRGB + MFMA QKV projection. (round-16 champion)
// LDS 21.2 KB (7 blocks/CU): K and Q stored DIRECTLY from transposed-MFMA
// accumulators as uint2 (32B-contiguous rows, L2-merged); only V needs the
// LDS transpose. Block 0 tail computes wcomb with w_out staged over dead LDS.
// ---------------------------------------------------------------------------
__global__ __launch_bounds__(256) void k_qkv(
    const float* __restrict__ x, const float* __restrict__ w_qkv,
    const float* __restrict__ w_high, const float* __restrict__ b_high,
    const float* __restrict__ gamma, const float* __restrict__ beta,
    const float* __restrict__ pos_q, const float* __restrict__ w_rgb,
    const float* __restrict__ w_out,
    float* __restrict__ featrgb, short* __restrict__ qmid,
    short* __restrict__ kbuf, short* __restrict__ vbuf,
    short* __restrict__ wcombb)
{
    __shared__ char smem[21248];
    short* XS  = (short*)smem;                 // [64][72] bf16 normalized acts
    short* TLv = (short*)(smem + 9216);        // [64][72] V staging (transpose)
    float* WL  = (float*)(smem + 18432);       // [64][8] conv/LN table
    float* WRL = (float*)(smem + 20480);       // [192] w_rgb

    const int tid = threadIdx.x, blk = blockIdx.x;
    const int bm = blk >> 8, p0 = (blk & 255) * 64;
    const int pixbase = blk * 64;
    const int wv = tid >> 6, lane = tid & 63;
    const int col = lane & 15, grp = lane >> 4;

    // ---- issue x loads FIRST (independent of LDS tables) ----
    const int px_l = tid >> 2, part = tid & 3;
    const int p_glob = p0 + px_l;
    const float* xp = x + (size_t)bm * 3 * HW + p_glob;
    const float x0 = xp[0], x1 = xp[HW], x2 = xp[2 * HW];

    // ---- build weight tables in LDS (tiny, L2-hot) ----
    if (tid < 64) {
        WL[tid * 8 + 0] = w_high[tid * 3];
        WL[tid * 8 + 1] = w_high[tid * 3 + 1];
        WL[tid * 8 + 2] = w_high[tid * 3 + 2];
        WL[tid * 8 + 3] = b_high[tid];
        WL[tid * 8 + 4] = gamma[tid];
        WL[tid * 8 + 5] = beta[tid];
    } else if (tid < 112) {
        ((float4*)WRL)[tid - 64] = ((const float4*)w_rgb)[tid - 64];
    }
    __syncthreads();

    // ---- conv + LN + rgb-residual: 4 threads/pixel, 16 channels each ----
    {
        float f[16]; float s = 0.f, s2 = 0.f;
        #pragma unroll
        for (int j = 0; j < 16; ++j) {
            const int ch = part * 16 + j;
            float4 wa = *(const float4*)&WL[ch * 8];
            f[j] = fmaf(wa.x, x0, fmaf(wa.y, x1, fmaf(wa.z, x2, wa.w)));
            s += f[j]; s2 = fmaf(f[j], f[j], s2);
        }
        float r0 = 0.f, r1 = 0.f, r2 = 0.f;
        #pragma unroll
        for (int j = 0; j < 16; ++j) {
            const float fj = f[j];
            r0 = fmaf(fj, WRL[part * 16 + j], r0);
            r1 = fmaf(fj, WRL[64 + part * 16 + j], r1);
            r2 = fmaf(fj, WRL[128 + part * 16 + j], r2);
        }
        s  += __shfl_xor(s, 1);  s  += __shfl_xor(s, 2);
        s2 += __shfl_xor(s2, 1); s2 += __shfl_xor(s2, 2);
        r0 += __shfl_xor(r0, 1); r0 += __shfl_xor(r0, 2);
        r1 += __shfl_xor(r1, 1); r1 += __shfl_xor(r1, 2);
        r2 += __shfl_xor(r2, 1); r2 += __shfl_xor(r2, 2);
        if (part < 3) {
            float rv = part == 0 ? r0 : (part == 1 ? r1 : r2);
            featrgb[((size_t)bm * 3 + part) * HW + p_glob] = rv;
        }
        const float mu = s * 0.015625f;
        const float var = s2 * 0.015625f - mu * mu;
        const float rs = rsqrtf(var + 1e-6f);
        unsigned xw[8];
        #pragma unroll
        for (int j2 = 0; j2 < 8; ++j2) {
            const int ch = part * 16 + 2 * j2;
            float4 g0 = *(const float4*)&WL[ch * 8 + 4];
            float4 g1 = *(const float4*)&WL[ch * 8 + 12];
            xw[j2] = pk2((f[2 * j2] - mu) * rs * g0.x + g0.y,
                         (f[2 * j2 + 1] - mu) * rs * g1.x + g1.y);
        }
        *(uint4*)&XS[px_l * 72 + part * 16]     = make_uint4(xw[0], xw[1], xw[2], xw[3]);
        *(uint4*)&XS[px_l * 72 + part * 16 + 8] = make_uint4(xw[4], xw[5], xw[6], xw[7]);
    }

    // ---- B-fragments packed from f32 w_qkv via float4 loads ----
    bf16x8 Bf[3][2];
    #pragma unroll
    for (int jj = 0; jj < 3; ++jj) {
        int jt = wv + jj * 4;
        #pragma unroll
        for (int kc = 0; kc < 2; ++kc) {
            const float4* src = (const float4*)&w_qkv[(jt * 16 + col) * 64 + kc * 32 + grp * 8];
            float4 a = src[0], b = src[1];
            union { bf16x8 v; unsigned u[4]; } tmp;
            tmp.u[0] = pk2(a.x, a.y); tmp.u[1] = pk2(a.z, a.w);
            tmp.u[2] = pk2(b.x, b.y); tmp.u[3] = pk2(b.z, b.w);
            Bf[jj][kc] = tmp.v;
        }
    }
    __syncthreads();

    // ---- MFMA projection; K and Q stored DIRECTLY to global ----
    #pragma unroll
    for (int pt = 0; pt < 4; ++pt) {
        bf16x8 A0 = *(const bf16x8*)&XS[(pt * 16 + col) * 72 + grp * 8];
        bf16x8 A1 = *(const bf16x8*)&XS[(pt * 16 + col) * 72 + 32 + grp * 8];

        f32x4 aK = {0.f, 0.f, 0.f, 0.f};
        aK = __builtin_amdgcn_mfma_f32_16x16x32_bf16(Bf[1][0], A0, aK, 0, 0, 0);
        aK = __builtin_amdgcn_mfma_f32_16x16x32_bf16(Bf[1][1], A1, aK, 0, 0, 0);
        uint2 kw = {pk2(aK[0], aK[1]), pk2(aK[2], aK[3])};
        *(uint2*)&kbuf[((size_t)pixbase + pt * 16 + col) * 64 + wv * 16 + grp * 4] = kw;

        f32x4 aV = {0.f, 0.f, 0.f, 0.f};
        aV = __builtin_amdgcn_mfma_f32_16x16x32_bf16(A0, Bf[2][0], aV, 0, 0, 0);
        aV = __builtin_amdgcn_mfma_f32_16x16x32_bf16(A1, Bf[2][1], aV, 0, 0, 0);
        #pragma unroll
        for (int i = 0; i < 4; ++i)
            TLv[(pt * 16 + grp * 4 + i) * 72 + wv * 16 + col] = f2b(aV[i]);

        if (bm == 2) {
            f32x4 aQ = {0.f, 0.f, 0.f, 0.f};
            aQ = __builtin_amdgcn_mfma_f32_16x16x32_bf16(Bf[0][0], A0, aQ, 0, 0, 0);
            aQ = __builtin_amdgcn_mfma_f32_16x16x32_bf16(Bf[0][1], A1, aQ, 0, 0, 0);
            int p = p0 + pt * 16 + col;
            int qq = ((p >> 7) & 7) * 8 + (p & 7);
            float4 pq = *(const float4*)&pos_q[qq * 64 + wv * 16 + grp * 4];
            uint2 qw = {pk2((aQ[0] + pq.x) * PRE, (aQ[1] + pq.y) * PRE),
                        pk2((aQ[2] + pq.z) * PRE, (aQ[3] + pq.w) * PRE)};
            *(uint2*)&qmid[((size_t)p0 + pt * 16 + col) * 64 + wv * 16 + grp * 4] = qw;
        }
    }
    __syncthreads();

    // ---- coalesced copy-out: V only ----
    #pragma unroll
    for (int it = 0; it < 2; ++it) {
        int j = it * 256 + tid;
        int row = j >> 3, seg = j & 7;
        *(uint4*)&vbuf[((size_t)pixbase + row) * 64 + seg * 8] =
            *(const uint4*)&TLv[row * 72 + seg * 8];
    }

    // ---- block 0 tail: wcomb = w_rgb @ w_out; f32 w_out over dead XS+TLv ----
    if (blk == 0) {
        float* WOL = (float*)smem;          // 16 KB spans XS+TLv (dead now)
        __syncthreads();                    // all copy-out LDS reads done
        for (int i = tid; i < 4096; i += 256) WOL[i] = w_out[i];
        __syncthreads();
        for (int i = tid; i < 1024; i += 256) {
            short wc = 0;
            if (i < 192) {
                int c = i >> 6, e = i & 63;
                float a = 0.f;
                #pragma unroll 8
                for (int e2 = 0; e2 < 64; ++e2)
                    a = fmaf(WRL[c * 64 + e2], WOL[e2 * 64 + e], a);
                wc = f2b(a);
            }
            wcombb[i] = wc;
        }
    }
}

// ---------------------------------------------------------------------------
// Kernel 2: windowed attention + fused epilogue — round-15/16 champion body.
// 512 threads, wave = head, wave-private barrier-free staging, no-max exp2
// softmax, P slot-buffer exchange, single barrier, MFMA epilogue.
// ---------------------------------------------------------------------------
__global__ __launch_bounds__(512, 4) void k_attn(
    const short* __restrict__ qmid, const short* __restrict__ kbuf,
    const short* __restrict__ vbuf,
    const float* __restrict__ pos_k, const float* __restrict__ b_rgb,
    const float* __restrict__ featrgb, const short* __restrict__ wcombb,
    float* __restrict__ outp)
{
    __shared__ char smem[48448];
    short* Klds = (short*)smem;                  // [144][72] bf16, K + pos_k
    short* Vt   = (short*)(smem + 20736);        // [64][152] bf16 + slack row 64
    short* OL   = (short*)smem;                  // overlay (head-column-sliced)
    // P slot buffers: smem + 40224, 1 KB per wave (8 waves)

    const int tid = threadIdx.x, blk = blockIdx.x;
    const int bm = blk >> 8, widx = blk & 255;
    const int wi = widx >> 4, wj = widx & 15;
    const int head = tid >> 6, lane = tid & 63;
    const int col = lane & 15, grp = lane >> 4;

    // ---- Q fragments first (independent loads, pos_q & scale pre-folded) ----
    uint4 qraw[4] = {{0,0,0,0},{0,0,0,0},{0,0,0,0},{0,0,0,0}};
    if (grp == 0) {
        #pragma unroll
        for (int qt = 0; qt < 4; ++qt) {
            int q = qt * 16 + col;
            int pix = (wi * 8 + (q >> 3)) * W_IMG + wj * 8 + (q & 7);
            qraw[qt] = *(const uint4*)&qmid[(size_t)pix * 64 + head * 8];
        }
    }

    // ---- wave-private staging: wave h covers keys lane, lane+64, lane+128 ----
    #pragma unroll
    for (int i = 0; i < 3; ++i) {
        const int kk = lane + i * 64;
        if (i == 2 && lane >= 16) continue;      // kk < 144
        const int r = kk / 12, c = kk - r * 12;
        const int hh = wi * 8 - 2 + r, ww = wj * 8 - 2 + c;
        uint4 kraw = {0, 0, 0, 0}, vraw = {0, 0, 0, 0};
        if ((unsigned)hh < 128u && (unsigned)ww < 128u) {
            size_t off = ((size_t)bm * HW + hh * W_IMG + ww) * 64 + head * 8;
            kraw = *(const uint4*)&kbuf[off];
            vraw = *(const uint4*)&vbuf[off];
        }
        const float* pk = &pos_k[kk * 64 + head * 8];
        float4 pk0 = *(const float4*)pk;
        float4 pk1 = *(const float4*)(pk + 4);
        union { uint4 q; short s[8]; } ku, vu;
        ku.q = kraw; vu.q = vraw;
        uint4 ko;
        ko.x = pk2(b2f(ku.s[0]) + pk0.x, b2f(ku.s[1]) + pk0.y);
        ko.y = pk2(b2f(ku.s[2]) + pk0.z, b2f(ku.s[3]) + pk0.w);
        ko.z = pk2(b2f(ku.s[4]) + pk1.x, b2f(ku.s[5]) + pk1.y);
        ko.w = pk2(b2f(ku.s[6]) + pk1.z, b2f(ku.s[7]) + pk1.w);
        *(uint4*)&Klds[kk * 72 + head * 8] = ko;
        #pragma unroll
        for (int cc = 0; cc < 8; ++cc)
            Vt[(head * 8 + cc) * 152 + kk] = vu.s[cc];
    }
    // zero this wave's Vt pad cols [144,152); wave 7 zeroes slack row 64 cols 0-7
    if (lane < 8) *(uint4*)&Vt[(head * 8 + lane) * 152 + 144] = (uint4){0, 0, 0, 0};
    if (head == 7 && lane == 0) *(uint4*)&Vt[64 * 152] = (uint4){0, 0, 0, 0};

    unsigned* PBh = (unsigned*)(smem + 40224 + head * 1024);
    const int slot_w = (grp * 16 + (col ^ grp)) * 4;
    const int g0 = 2 * (grp & 1);
    const int slotr1 = (g0 * 16 + (col ^ g0)) * 4 + (grp >> 1) * 2;
    const int slotr2 = ((g0 + 1) * 16 + (col ^ (g0 + 1))) * 4 + (grp >> 1) * 2;

    f32x4 oacc[4];
    float linv[4];

    #pragma unroll
    for (int qt = 0; qt < 4; ++qt) {
        union { bf16x8 v; uint4 r; } qu; qu.r = qraw[qt];
        const bf16x8 qf = qu.v;

        // ---- softmax, no max-subtract: p = exp2(s) directly ----
        float l = 0.f;
        unsigned pw[20];
        __builtin_amdgcn_s_setprio(1);
        #pragma unroll
        for (int t = 0; t < 9; ++t) {
            bf16x8 kf = *(const bf16x8*)&Klds[(t * 16 + col) * 72 + head * 8];
            f32x4 sct = __builtin_amdgcn_mfma_f32_16x16x32_bf16(
                kf, qf, (f32x4){0.f, 0.f, 0.f, 0.f}, 0, 0, 0);
            float e0 = fexp2(sct[0]), e1 = fexp2(sct[1]);
            float e2 = fexp2(sct[2]), e3 = fexp2(sct[3]);
            l += (e0 + e1) + (e2 + e3);
            pw[2 * t]     = pk2(e0, e1);
            pw[2 * t + 1] = pk2(e2, e3);
        }
        __builtin_amdgcn_s_setprio(0);
        pw[18] = 0u; pw[19] = 0u;
        l += __shfl_xor(l, 16);
        l += __shfl_xor(l, 32);
        linv[qt] = __builtin_amdgcn_rcpf(l);

        // ---- PV: O^T = V^T . P^T, P via slot-buffer exchange ----
        *(uint4*)(PBh + slot_w) = make_uint4(pw[0], pw[1], pw[2], pw[3]);
        f32x4 oa = {0.f, 0.f, 0.f, 0.f};
        __builtin_amdgcn_s_setprio(1);
        #pragma unroll
        for (int kt2 = 0; kt2 < 5; ++kt2) {
            uint2 r1 = *(const uint2*)(PBh + slotr1);
            uint2 r2 = *(const uint2*)(PBh + slotr2);
            if (kt2 < 4)
                *(uint4*)(PBh + slot_w) =
                    make_uint4(pw[4 * kt2 + 4], pw[4 * kt2 + 5], pw[4 * kt2 + 6], pw[4 * kt2 + 7]);
            union { bf16x8 v; unsigned u[4]; } pf;
            pf.u[0] = r1.x; pf.u[1] = r1.y; pf.u[2] = r2.x; pf.u[3] = r2.y;
            bf16x8 vf = *(const bf16x8*)&Vt[(head * 8 + (lane & 7)) * 152 + kt2 * 32 + grp * 8];
            oa = __builtin_amdgcn_mfma_f32_16x16x32_bf16(vf, pf.v, oa, 0, 0, 0);
        }
        __builtin_amdgcn_s_setprio(0);
        oacc[qt] = oa;
    }

    // ---- OL write: overlays THIS wave's own Klds column slice (in-order) ----
    if (grp < 2) {
        #pragma unroll
        for (int qt = 0; qt < 4; ++qt) {
            float s = linv[qt];
            uint2 ow;
            ow.x = pk2(oacc[qt][0] * s, oacc[qt][1] * s);
            ow.y = pk2(oacc[qt][2] * s, oacc[qt][3] * s);
            *(uint2*)&OL[(qt * 16 + col) * 72 + head * 8 + grp * 4] = ow;
        }
    }
    __syncthreads();   // the ONLY barrier: epilogue reads OL across heads

    // ---- fused epilogue: rgb = O@wcomb^T + featrgb + b_rgb (waves 0-3) ----
    if (head < 4) {
        const int qt = head;
        f32x4 acc = {0.f, 0.f, 0.f, 0.f};
        #pragma unroll
        for (int kc = 0; kc < 2; ++kc) {
            bf16x8 ao = *(const bf16x8*)&OL[(qt * 16 + col) * 72 + kc * 32 + grp * 8];
            bf16x8 bo = *(const bf16x8*)&wcombb[col * 64 + kc * 32 + grp * 8];
            acc = __builtin_amdgcn_mfma_f32_16x16x32_bf16(ao, bo, acc, 0, 0, 0);
        }
        if (col < 3) {
            float br = b_rgb[col];
            const float* frp = featrgb + ((size_t)bm * 3 + col) * HW;
            #pragma unroll
            for (int i = 0; i < 4; ++i) {
                int qs = qt * 16 + grp * 4 + i;
                int pix = (wi * 8 + (qs >> 3)) * W_IMG + wj * 8 + (qs & 7);
                outp[(size_t)bm * 3 * HW + col * HW + pix] = acc[i] + frp[pix] + br;
            }
        }
    }
}

// ---------------------------------------------------------------------------
extern "C" void kernel_launch(void* const* d_in, const int* in_sizes, int n_in,
                              void* d_out, int out_size, void* d_ws, size_t ws_size,
                              hipStream_t stream) {
    const float* x      = (const float*)d_in[0];
    const float* w_high = (const float*)d_in[1];
    const float* b_high = (const float*)d_in[2];
    const float* gamma  = (const float*)d_in[3];
    const float* beta   = (const float*)d_in[4];
    const float* w_qkv  = (const float*)d_in[5];
    const float* pos_q  = (const float*)d_in[6];
    const float* pos_k  = (const float*)d_in[7];
    const float* w_out  = (const float*)d_in[8];
    const float* w_rgb  = (const float*)d_in[9];
    const float* b_rgb  = (const float*)d_in[10];
    float* out = (float*)d_out;

    float* featrgb = (float*)d_ws;                         // [5][3][HW] f32
    short* kbuf    = (short*)(featrgb + (size_t)BM_TOT * 3 * HW);
    short* vbuf    = kbuf + (size_t)BM_TOT * HW * 64;
    short* qmid    = vbuf + (size_t)BM_TOT * HW * 64;      // [HW][64]
    short* wcombb  = qmid + (size_t)HW * 64;               // [16][64]

    k_qkv<<<BM_TOT * 256, 256, 0, stream>>>(x, w_qkv, w_high, b_high, gamma, beta,
                                            pos_q, w_rgb, w_out,
                                            featrgb, qmid, kbuf, vbuf, wcombb);
    k_attn<<<BM_TOT * 256, 512, 0, stream>>>(qmid, kbuf, vbuf, pos_k,
                                             b_rgb, featrgb, wcombb, out);
}